// Round 1
// baseline (827.176 us; speedup 1.0000x reference)
//
#include <hip/hip_runtime.h>
#include <stdint.h>

#define NV 4096
#define NE 8192
#define FV 128
#define FE 64
#define FOUT 128

typedef unsigned short u16;
typedef __attribute__((ext_vector_type(8))) short short8;
typedef __attribute__((ext_vector_type(4))) float f32x4;
typedef __attribute__((ext_vector_type(4))) unsigned short u16x4;

__device__ __forceinline__ u16 f2bf(float f) {
  uint32_t u = __builtin_bit_cast(uint32_t, f);
  u += 0x7fffu + ((u >> 16) & 1u);   // round-to-nearest-even
  return (u16)(u >> 16);
}

#define AS1(p) ((__attribute__((address_space(1))) void*)(void*)(p))
#define AS3(p) ((__attribute__((address_space(3))) void*)(p))

// ---------------------------------------------------------------- d[e] = dot(H_e[e,:], p)
__global__ __launch_bounds__(64) void k_edge_dot(const float* __restrict__ He,
                                                 const float* __restrict__ p,
                                                 float* __restrict__ d) {
  int e = blockIdx.x;
  int l = threadIdx.x;
  float v = He[e * FE + l] * p[l];
  #pragma unroll
  for (int off = 32; off > 0; off >>= 1) v += __shfl_down(v, off);
  if (l == 0) d[e] = v;
}

// --------------------------------------- Ta = bf16(T * d[col]), Tb = bf16(T)  (both [NV][NE], K-major)
__global__ __launch_bounds__(256) void k_convert(const float* __restrict__ T,
                                                 const float* __restrict__ d,
                                                 u16* __restrict__ Ta,
                                                 u16* __restrict__ Tb) {
  size_t idx = ((size_t)blockIdx.x * 256 + threadIdx.x) * 4;
  f32x4 t = *(const f32x4*)&T[idx];
  int e = (int)(idx & (NE - 1));
  f32x4 dv = *(const f32x4*)&d[e];
  u16x4 a, b;
  a.x = f2bf(t.x * dv.x); a.y = f2bf(t.y * dv.y);
  a.z = f2bf(t.z * dv.z); a.w = f2bf(t.w * dv.w);
  b.x = f2bf(t.x); b.y = f2bf(t.y); b.z = f2bf(t.z); b.w = f2bf(t.w);
  *(u16x4*)&Ta[idx] = a;
  *(u16x4*)&Tb[idx] = b;
}

// ---------------------------- HWt[n][i] = bf16( sum_f Hv[i][f] * W[f][n] )  ([FOUT][NV], K-major for gemm_out)
__global__ __launch_bounds__(128) void k_hw(const float* __restrict__ Hv,
                                            const float* __restrict__ W,
                                            u16* __restrict__ HWt) {
  __shared__ float sh[FV];
  int i = blockIdx.x;
  int n = threadIdx.x;
  sh[n] = Hv[i * FV + n];
  __syncthreads();
  float s = 0.f;
  #pragma unroll
  for (int f = 0; f < FV; ++f) s += sh[f] * W[f * FOUT + n];
  HWt[(size_t)n * NV + i] = f2bf(s);
}

// ------------------------- out[0:NV*FOUT) = bias bcast; out[NV*FOUT:) = H_e copy (2nd tuple output)
__global__ __launch_bounds__(256) void k_init_out(float* __restrict__ out,
                                                  const float* __restrict__ bias,
                                                  const float* __restrict__ He) {
  int idx = blockIdx.x * 256 + threadIdx.x;
  if (idx < NV * FOUT) out[idx] = bias[idx & (FOUT - 1)];
  else out[idx] = He[idx - NV * FOUT];
}

// ---------------------------------------------------------------------------
// adjA[i][j] = bf16( ((i==j) ? 1 : sum_e Ta[i][e]*Tb[j][e]) * adjv[i][j] )
// m97 structure: 128x128 tile, BK=32, 4 waves in 2x2, 4x4 16x16x32 bf16 MFMA / wave,
// global_load_lds width=16 with wave-uniform LDS base + lane*16.
// ---------------------------------------------------------------------------
__global__ __launch_bounds__(256) void k_gemm_mult(const u16* __restrict__ Ta,
                                                   const u16* __restrict__ Tb,
                                                   const float* __restrict__ adjv,
                                                   u16* __restrict__ adjA) {
  __shared__ __align__(16) u16 lA[128 * 32];
  __shared__ __align__(16) u16 lB[128 * 32];
  const int K = NE;
  const int tile_m = blockIdx.y * 128;
  const int tile_n = blockIdx.x * 128;
  const int tid = threadIdx.x;
  const int lane = tid & 63;
  const int wave = tid >> 6;
  const int wm = (wave >> 1) * 64;
  const int wn = (wave & 1) * 64;
  const int row16 = lane & 15;
  const int quad = lane >> 4;

  f32x4 acc[4][4] = {};

  for (int k0 = 0; k0 < K; k0 += 32) {
    __syncthreads();
    #pragma unroll
    for (int r = 0; r < 2; ++r) {
      const int chunk = r * 256 + wave * 64 + lane;   // 16B chunk id, 512 per tile
      const int row = chunk >> 2;                     // 4 chunks per 32-elem row
      const int cc = chunk & 3;
      const u16* ga = Ta + ((size_t)(tile_m + row) * K + k0 + cc * 8);
      const u16* gb = Tb + ((size_t)(tile_n + row) * K + k0 + cc * 8);
      __builtin_amdgcn_global_load_lds(AS1(ga), AS3(&lA[(r * 256 + wave * 64) * 8]), 16, 0, 0);
      __builtin_amdgcn_global_load_lds(AS1(gb), AS3(&lB[(r * 256 + wave * 64) * 8]), 16, 0, 0);
    }
    __syncthreads();
    short8 a[4], b[4];
    #pragma unroll
    for (int mi = 0; mi < 4; ++mi)
      a[mi] = *(const short8*)&lA[(wm + mi * 16 + row16) * 32 + quad * 8];
    #pragma unroll
    for (int ni = 0; ni < 4; ++ni)
      b[ni] = *(const short8*)&lB[(wn + ni * 16 + row16) * 32 + quad * 8];
    #pragma unroll
    for (int mi = 0; mi < 4; ++mi)
      #pragma unroll
      for (int ni = 0; ni < 4; ++ni)
        acc[mi][ni] = __builtin_amdgcn_mfma_f32_16x16x32_bf16(a[mi], b[ni], acc[mi][ni], 0, 0, 0);
  }

  // epilogue: C/D layout col=lane&15, row=quad*4+reg (verified m89/m91)
  #pragma unroll
  for (int mi = 0; mi < 4; ++mi) {
    #pragma unroll
    for (int ni = 0; ni < 4; ++ni) {
      const int gc = tile_n + wn + ni * 16 + row16;
      #pragma unroll
      for (int r = 0; r < 4; ++r) {
        const int gr = tile_m + wm + mi * 16 + quad * 4 + r;
        float v = acc[mi][ni][r];
        if (gr == gc) v = 1.0f;                 // eye mask: diag of M1 is exactly 1
        v *= adjv[(size_t)gr * NV + gc];
        adjA[(size_t)gr * NV + gc] = f2bf(v);
      }
    }
  }
}

// ---------------------------------------------------------------------------
// out[i][n] += sum_k adjA[i][k] * HWt[n][k]   (K-split over 8 blocks, fp32 atomics;
// bias was pre-initialized by k_init_out)
// ---------------------------------------------------------------------------
#define KSPLIT 8
__global__ __launch_bounds__(256) void k_gemm_out(const u16* __restrict__ A,
                                                  const u16* __restrict__ B,
                                                  float* __restrict__ out) {
  __shared__ __align__(16) u16 lA[128 * 32];
  __shared__ __align__(16) u16 lB[128 * 32];
  const int K = NV;
  const int tile_m = blockIdx.y * 128;
  const int kbeg = blockIdx.x * (K / KSPLIT);
  const int kend = kbeg + (K / KSPLIT);
  const int tid = threadIdx.x;
  const int lane = tid & 63;
  const int wave = tid >> 6;
  const int wm = (wave >> 1) * 64;
  const int wn = (wave & 1) * 64;
  const int row16 = lane & 15;
  const int quad = lane >> 4;

  f32x4 acc[4][4] = {};

  for (int k0 = kbeg; k0 < kend; k0 += 32) {
    __syncthreads();
    #pragma unroll
    for (int r = 0; r < 2; ++r) {
      const int chunk = r * 256 + wave * 64 + lane;
      const int row = chunk >> 2;
      const int cc = chunk & 3;
      const u16* ga = A + ((size_t)(tile_m + row) * K + k0 + cc * 8);
      const u16* gb = B + ((size_t)row * K + k0 + cc * 8);   // N=128: full B tile
      __builtin_amdgcn_global_load_lds(AS1(ga), AS3(&lA[(r * 256 + wave * 64) * 8]), 16, 0, 0);
      __builtin_amdgcn_global_load_lds(AS1(gb), AS3(&lB[(r * 256 + wave * 64) * 8]), 16, 0, 0);
    }
    __syncthreads();
    short8 a[4], b[4];
    #pragma unroll
    for (int mi = 0; mi < 4; ++mi)
      a[mi] = *(const short8*)&lA[(wm + mi * 16 + row16) * 32 + quad * 8];
    #pragma unroll
    for (int ni = 0; ni < 4; ++ni)
      b[ni] = *(const short8*)&lB[(wn + ni * 16 + row16) * 32 + quad * 8];
    #pragma unroll
    for (int mi = 0; mi < 4; ++mi)
      #pragma unroll
      for (int ni = 0; ni < 4; ++ni)
        acc[mi][ni] = __builtin_amdgcn_mfma_f32_16x16x32_bf16(a[mi], b[ni], acc[mi][ni], 0, 0, 0);
  }

  #pragma unroll
  for (int mi = 0; mi < 4; ++mi) {
    #pragma unroll
    for (int ni = 0; ni < 4; ++ni) {
      const int gc = wn + ni * 16 + row16;      // tile_n = 0, N = 128
      #pragma unroll
      for (int r = 0; r < 4; ++r) {
        const int gr = tile_m + wm + mi * 16 + quad * 4 + r;
        atomicAdd(&out[(size_t)gr * FOUT + gc], acc[mi][ni][r]);
      }
    }
  }
}

extern "C" void kernel_launch(void* const* d_in, const int* in_sizes, int n_in,
                              void* d_out, int out_size, void* d_ws, size_t ws_size,
                              hipStream_t stream) {
  const float* Hv   = (const float*)d_in[0];
  const float* He   = (const float*)d_in[1];
  // d_in[2] = adj_e : unused in node_layer=True path
  const float* adjv = (const float*)d_in[3];
  const float* T    = (const float*)d_in[4];
  const float* W    = (const float*)d_in[5];
  const float* p    = (const float*)d_in[6];
  const float* bias = (const float*)d_in[7];
  float* out = (float*)d_out;

  // ws layout (needs ~162 MB):
  //   [0,32KB)           d vector (fp32)
  //   [1MB,2MB)          HWt bf16  (128*4096)
  //   [2MB,66MB)         Ta bf16   (4096*8192, T*d)
  //   [66MB,130MB)       Tb bf16   (4096*8192, T)
  //   [130MB,162MB)      adjA bf16 (4096*4096)
  char* ws = (char*)d_ws;
  float* dvec = (float*)ws;
  u16* HWt  = (u16*)(ws + ((size_t)1 << 20));
  u16* Ta   = (u16*)(ws + ((size_t)2 << 20));
  u16* Tb   = (u16*)(ws + ((size_t)2 << 20) + ((size_t)64 << 20));
  u16* adjA = (u16*)(ws + ((size_t)2 << 20) + ((size_t)128 << 20));

  k_edge_dot<<<NE, 64, 0, stream>>>(He, p, dvec);
  k_convert<<<(NV * NE) / (256 * 4), 256, 0, stream>>>(T, dvec, Ta, Tb);
  k_hw<<<NV, 128, 0, stream>>>(Hv, W, HWt);
  k_init_out<<<(NV * FOUT + NE * FE) / 256, 256, 0, stream>>>(out, bias, He);
  k_gemm_mult<<<dim3(NV / 128, NV / 128), 256, 0, stream>>>(Ta, Tb, adjv, adjA);
  k_gemm_out<<<dim3(KSPLIT, NV / 128), 256, 0, stream>>>(adjA, HWt, out);
}